// Round 4
// baseline (337.664 us; speedup 1.0000x reference)
//
#include <hip/hip_runtime.h>
#include <hip/hip_bf16.h>

// Problem constants (B=4, S=4096, D=1024)
#define BB 4
#define SS 4096
#define DD 1024
#define MM (BB * SS)   // 16384 rows
#define KK DD          // 1024  reduction dim
#define NN (4 * DD)    // 4096  cols (permuted): [q | kv-interleaved | gate]

typedef __attribute__((ext_vector_type(8))) short bf16x8;
typedef __attribute__((ext_vector_type(4))) float f32x4;

__device__ __forceinline__ unsigned short f2bf(float f) {
  unsigned u = __float_as_uint(f);
  u += 0x7FFF + ((u >> 16) & 1);   // RNE
  return (unsigned short)(u >> 16);
}
__device__ __forceinline__ float bf2f(unsigned short h) {
  return __uint_as_float(((unsigned)h) << 16);
}

// ---------------------------------------------------------------- convert f32 -> bf16
__global__ __launch_bounds__(256) void k_convert(const float* __restrict__ src,
                                                 unsigned short* __restrict__ dst, int n4) {
  int i = blockIdx.x * blockDim.x + threadIdx.x;
  int stride = gridDim.x * blockDim.x;
  for (; i < n4; i += stride) {
    float4 v = reinterpret_cast<const float4*>(src)[i];
    ushort4 o;
    o.x = f2bf(v.x); o.y = f2bf(v.y); o.z = f2bf(v.z); o.w = f2bf(v.w);
    reinterpret_cast<ushort4*>(dst)[i] = o;
  }
}

// Weight permutation (row n' of Wb): [0,1024)=q rows; [1024,3072)=16-col k/v interleave;
// [3072,4096)=gate rows.
__global__ __launch_bounds__(256) void k_convert_wperm(const float* __restrict__ Wqkv,
                                                       const float* __restrict__ Wgate,
                                                       unsigned short* __restrict__ dst) {
  int n = blockIdx.x;
  const float* src;
  if (n < 1024) {
    src = Wqkv + (size_t)n * 1024;
  } else if (n < 3072) {
    int t = (n - 1024) >> 4;
    int d = ((t >> 1) << 4) + (n & 15);
    src = Wqkv + (size_t)(1024 + ((t & 1) << 10) + d) * 1024;
  } else {
    src = Wgate + (size_t)(n - 3072) * 1024;
  }
  unsigned short* o = dst + (size_t)n * 1024;
  int i = threadIdx.x * 4;
  float4 v = *(const float4*)(src + i);
  ushort4 u;
  u.x = f2bf(v.x); u.y = f2bf(v.y); u.z = f2bf(v.z); u.w = f2bf(v.w);
  *(ushort4*)(o + i) = u;
}

// ---------------------------------------------------------------- 256x256 8-phase GEMM (m201 template)
// BM=BN=256, BK=64, 8 waves (2Mx4N), per-wave 128x64 out (8x4 frags).
// LDS 128KiB: A[2dbuf][2half][128][64]bf16 + B same. st_16x32 swizzle
// (byte ^= ((byte>>9)&1)<<5 within each half-tile): inverse-swizzled global
// source + linear global_load_lds dest + swizzled ds_read (rule 21).
// 8 phases / 2 K-tiles; counted vmcnt(4) at ph4/ph8 only.
#define VMW4() asm volatile("s_waitcnt vmcnt(4)" ::: "memory")
#define VMW0() asm volatile("s_waitcnt vmcnt(0)" ::: "memory")

__global__ __launch_bounds__(512, 2) void k_gemm3(const unsigned short* __restrict__ A,
                                                  const unsigned short* __restrict__ W,
                                                  unsigned short* __restrict__ Qd,
                                                  unsigned short* __restrict__ KVd,
                                                  unsigned short* __restrict__ Gd,
                                                  const float* __restrict__ bqkv,
                                                  const float* __restrict__ bgate) {
  __shared__ unsigned short sm[65536];  // 128 KiB

  int bid0 = blockIdx.x;
  int bid = (bid0 & 7) * 128 + (bid0 >> 3);   // XCD swizzle (nwg=1024 %8==0 -> bijective)
  int tn = bid & 15, tm = bid >> 4;
  int m0 = tm * 256, n0 = tn * 256;

  int tid = threadIdx.x, wave = tid >> 6, lane = tid & 63;
  int wm = wave >> 2, wn = wave & 3;
  int r = lane & 15, g = lane >> 4;

  // ---- staging source (per-lane, inverse-swizzled). Half-tile linear byte p = c*8192 + tid*16.
  // bit9(p) == bit9(tid*16) for both rounds -> same per-thread swizzle.
  int pt = tid * 16;
  int psw = pt ^ (((pt >> 9) & 1) << 5);
  int srow = psw >> 7;          // 0..63 (round c adds 64 rows)
  int scol = (psw & 127) >> 1;  // ushort col within 64-col K-slice
  const unsigned short* Ag = A + (size_t)(m0 + srow) * KK + scol;
  const unsigned short* Wg = W + (size_t)(n0 + srow) * KK + scol;

  // Stage one half-tile = 2 x global_load_lds_dwordx4 per thread.
  // LDS dest (ushort): A: d*16384 + h*8192 + c*4096 + wave*512 ; B: +32768.
#define STG_A(kt, h, d) do {                                                              \
    __builtin_amdgcn_global_load_lds(                                                     \
        (const __attribute__((address_space(1))) void*)(Ag + (size_t)(h)*131072 + (kt)*64), \
        (__attribute__((address_space(3))) void*)&sm[(d)*16384 + (h)*8192 + wave*512], 16, 0, 0); \
    __builtin_amdgcn_global_load_lds(                                                     \
        (const __attribute__((address_space(1))) void*)(Ag + (size_t)(h)*131072 + 65536 + (kt)*64), \
        (__attribute__((address_space(3))) void*)&sm[(d)*16384 + (h)*8192 + 4096 + wave*512], 16, 0, 0); \
  } while (0)
#define STG_B(kt, h, d) do {                                                              \
    __builtin_amdgcn_global_load_lds(                                                     \
        (const __attribute__((address_space(1))) void*)(Wg + (size_t)(h)*131072 + (kt)*64), \
        (__attribute__((address_space(3))) void*)&sm[32768 + (d)*16384 + (h)*8192 + wave*512], 16, 0, 0); \
    __builtin_amdgcn_global_load_lds(                                                     \
        (const __attribute__((address_space(1))) void*)(Wg + (size_t)(h)*131072 + 65536 + (kt)*64), \
        (__attribute__((address_space(3))) void*)&sm[32768 + (d)*16384 + (h)*8192 + 4096 + wave*512], 16, 0, 0); \
  } while (0)

  // ---- ds_read bases (swizzled). Linear ushort pos: row*64 + ks*32 + g*8 (+region).
  // bit9(byte) == bit2(rowL) == (r>>2)&1 for all frags -> per-lane constant XOR of 16 ushorts.
  int sx = ((r >> 2) & 1) << 4;
  int aRd = (wm * 8192 + r * 64 + g * 8) ^ sx;                              // + d*16384 + m*1024 + ks*32
  int bRd = (32768 + (wn >> 1) * 8192 + (wn & 1) * 4096 + r * 64 + g * 8) ^ sx;  // + d*16384 + n*1024 + ks*32

#define LDSA(d, m, ks) (*reinterpret_cast<const bf16x8*>(&sm[aRd + (d)*16384 + (m)*1024 + (ks)*32]))
#define LDSB(d, n, ks) (*reinterpret_cast<const bf16x8*>(&sm[bRd + (d)*16384 + (n)*1024 + (ks)*32]))

  f32x4 acc[8][4] = {};
  bf16x8 a[4][2], Bn[4][2];

#define RD_A(d, mb) do { _Pragma("unroll") for (int mi = 0; mi < 4; ++mi) {               \
    _Pragma("unroll") for (int ks = 0; ks < 2; ++ks) { a[mi][ks] = LDSA(d, (mb)+mi, ks); } } } while (0)
#define RD_B(d, nb) do { _Pragma("unroll") for (int ni = 0; ni < 2; ++ni) {               \
    _Pragma("unroll") for (int ks = 0; ks < 2; ++ks) { Bn[(nb)+ni][ks] = LDSB(d, (nb)+ni, ks); } } } while (0)

#define BARW() do { __builtin_amdgcn_s_barrier();                                         \
    asm volatile("s_waitcnt lgkmcnt(0)" ::: "memory");                                    \
    __builtin_amdgcn_sched_barrier(0); } while (0)
#define ENDB() __builtin_amdgcn_s_barrier()

#define MFMA16(mb, nb) do {                                                               \
    __builtin_amdgcn_s_setprio(1);                                                        \
    _Pragma("unroll") for (int mi = 0; mi < 4; ++mi) {                                    \
      _Pragma("unroll") for (int ni = 0; ni < 2; ++ni) {                                  \
        _Pragma("unroll") for (int ks = 0; ks < 2; ++ks) {                                \
          acc[(mb)+mi][(nb)+ni] = __builtin_amdgcn_mfma_f32_16x16x32_bf16(                \
              a[mi][ks], Bn[(nb)+ni][ks], acc[(mb)+mi][(nb)+ni], 0, 0, 0);                \
        } } }                                                                             \
    __builtin_amdgcn_s_setprio(0); } while (0)

  // ---- prologue: T0 (dbuf0, all 4 half-tiles) + B-T1 (dbuf1 halves)
  STG_A(0, 0, 0); STG_A(0, 1, 0);
  STG_B(0, 0, 0); STG_B(0, 1, 0);
  STG_B(1, 0, 1); STG_B(1, 1, 1);
  VMW4();                      // T0 landed; B-T1 may be in flight
  __builtin_amdgcn_s_barrier();

  // ---- main loop: 7 iterations, 2 K-tiles each (T0..T13); peeled final (T14,T15)
  for (int i = 0; i < 7; ++i) {
    int tb = 2 * i + 1, tc = 2 * i + 2, td = 2 * i + 3;
    // ph1: Q(m0-3,n0-1) dbuf0 ; stage A-Tb-h0
    RD_A(0, 0); RD_B(0, 0); STG_A(tb, 0, 1);
    BARW(); MFMA16(0, 0); ENDB();
    // ph2: Q(m0-3,n2-3) ; stage A-Tb-h1
    RD_B(0, 2); STG_A(tb, 1, 1);
    BARW(); MFMA16(0, 2); ENDB();
    // ph3: Q(m4-7,n0-1) ; stage B-Tc-h0 (B-Ta free after ph2)
    RD_A(0, 4); STG_B(tc, 0, 0);
    BARW(); MFMA16(4, 0); ENDB();
    // ph4: Q(m4-7,n2-3) ; stage B-Tc-h1 ; vmcnt(4) -> A-Tb landed for ph5
    STG_B(tc, 1, 0);
    BARW(); MFMA16(4, 2); VMW4(); ENDB();
    // ph5: Q(m0-3,n0-1) dbuf1 ; stage A-Tc-h0 (A-Ta free after ph3)
    RD_A(1, 0); RD_B(1, 0); STG_A(tc, 0, 0);
    BARW(); MFMA16(0, 0); ENDB();
    // ph6 ; stage A-Tc-h1
    RD_B(1, 2); STG_A(tc, 1, 0);
    BARW(); MFMA16(0, 2); ENDB();
    // ph7 ; stage B-Td-h0 (B-Tb free after ph6)
    RD_A(1, 4); STG_B(td, 0, 1);
    BARW(); MFMA16(4, 0); ENDB();
    // ph8 ; stage B-Td-h1 ; vmcnt(4) -> Tc fully landed for next ph1
    STG_B(td, 1, 1);
    BARW(); MFMA16(4, 2); VMW4(); ENDB();
  }
  // ---- peeled final iteration (T14 dbuf0, T15 dbuf1); only A-T15 staging remains
  RD_A(0, 0); RD_B(0, 0); STG_A(15, 0, 1);
  BARW(); MFMA16(0, 0); ENDB();
  RD_B(0, 2); STG_A(15, 1, 1);
  BARW(); MFMA16(0, 2); ENDB();
  RD_A(0, 4);
  BARW(); MFMA16(4, 0); ENDB();
  BARW(); MFMA16(4, 2); VMW0(); ENDB();
  RD_A(1, 0); RD_B(1, 0);
  BARW(); MFMA16(0, 0); ENDB();
  RD_B(1, 2);
  BARW(); MFMA16(0, 2); ENDB();
  RD_A(1, 4);
  BARW(); MFMA16(4, 0); ENDB();
  BARW(); MFMA16(4, 2);

  // ---- epilogue (same as round 3; C/D layout col=lane&15, row=(lane>>4)*4+q)
  int growb = m0 + wm * 128 + g * 4;
  if (tn < 4) {
#pragma unroll
    for (int n = 0; n < 4; ++n) {
      int col = n0 + wn * 64 + n * 16 + r;
      float bias = bqkv[col];
#pragma unroll
      for (int m = 0; m < 8; ++m)
#pragma unroll
        for (int q = 0; q < 4; ++q)
          Qd[(size_t)(growb + m * 16 + q) * DD + col] = f2bf(acc[m][n][q] + bias);
    }
  } else if (tn < 12) {
    int cb = n0 - 1024 + wn * 64;
#pragma unroll
    for (int np = 0; np < 2; ++np) {
      int d = (cb >> 1) + np * 16 + r;
      float bk = bqkv[1024 + d], bv = bqkv[2048 + d];
#pragma unroll
      for (int m = 0; m < 8; ++m)
#pragma unroll
        for (int q = 0; q < 4; ++q) {
          float kvv = (acc[m][2 * np][q] + bk) * (acc[m][2 * np + 1][q] + bv);
          KVd[(size_t)(growb + m * 16 + q) * DD + d] = f2bf(kvv);
        }
    }
  } else {
    int cb0 = n0 - 3072;
#pragma unroll
    for (int n = 0; n < 4; ++n) {
      int c = cb0 + wn * 64 + n * 16 + r;
      float bias = bgate[c];
#pragma unroll
      for (int m = 0; m < 8; ++m)
#pragma unroll
        for (int q = 0; q < 4; ++q) {
          float gv = acc[m][n][q] + bias;
          Gd[(size_t)(growb + m * 16 + q) * DD + c] = f2bf(1.f / (1.f + __expf(-gv)));
        }
    }
  }
#undef STG_A
#undef STG_B
#undef LDSA
#undef LDSB
#undef RD_A
#undef RD_B
#undef BARW
#undef ENDB
#undef MFMA16
}

// ---------------------------------------------------------------- chunked scan over S
#define NCH 128
#define CSZ (SS / NCH)  // 32

// pass1: per-chunk partial sums of kv per (b,d)
__global__ __launch_bounds__(256) void k_pass1(const unsigned short* __restrict__ KV,
                                               float* __restrict__ part) {
  int b = blockIdx.x >> 7;
  int c = blockIdx.x & (NCH - 1);
  int d = threadIdx.x * 4;
  float a0 = 0.f, a1 = 0.f, a2 = 0.f, a3 = 0.f;
  for (int s = c * CSZ; s < (c + 1) * CSZ; ++s) {
    ushort4 kv = *(const ushort4*)&KV[(size_t)(b * SS + s) * DD + d];
    a0 += bf2f(kv.x); a1 += bf2f(kv.y); a2 += bf2f(kv.z); a3 += bf2f(kv.w);
  }
  float4 o = {a0, a1, a2, a3};
  *(float4*)&part[(size_t)(b * NCH + c) * DD + d] = o;
}

// pass3: on-the-fly exclusive chunk prefix (part is L2/L3-resident, independent loads)
// + local cumsum + out = q * kv_state * g (g pre-sigmoided)
__global__ __launch_bounds__(256) void k_pass3(const unsigned short* __restrict__ Q,
                                               const unsigned short* __restrict__ KV,
                                               const unsigned short* __restrict__ G,
                                               const float* __restrict__ part,
                                               float* __restrict__ out) {
  int b = blockIdx.x >> 7;
  int c = blockIdx.x & (NCH - 1);
  int d = threadIdx.x * 4;
  float4 a = {0.f, 0.f, 0.f, 0.f};
  const float* pb = &part[(size_t)b * NCH * DD + d];
  for (int cc = 0; cc < c; ++cc) {
    float4 p = *(const float4*)(pb + (size_t)cc * DD);
    a.x += p.x; a.y += p.y; a.z += p.z; a.w += p.w;
  }
  for (int s = c * CSZ; s < (c + 1) * CSZ; ++s) {
    size_t rowb = (size_t)(b * SS + s) * DD;
    ushort4 q4 = *(const ushort4*)&Q[rowb + d];
    ushort4 kv4 = *(const ushort4*)&KV[rowb + d];
    ushort4 g4 = *(const ushort4*)&G[rowb + d];
    a.x += bf2f(kv4.x); a.y += bf2f(kv4.y); a.z += bf2f(kv4.z); a.w += bf2f(kv4.w);
    float4 o;
    o.x = bf2f(q4.x) * a.x * bf2f(g4.x);
    o.y = bf2f(q4.y) * a.y * bf2f(g4.y);
    o.z = bf2f(q4.z) * a.z * bf2f(g4.z);
    o.w = bf2f(q4.w) * a.w * bf2f(g4.w);
    *(float4*)&out[rowb + d] = o;
  }
}

// ---------------------------------------------------------------- launch
extern "C" void kernel_launch(void* const* d_in, const int* in_sizes, int n_in,
                              void* d_out, int out_size, void* d_ws, size_t ws_size,
                              hipStream_t stream) {
  const float* x = (const float*)d_in[0];      // [B,S,D]
  const float* Wqkv = (const float*)d_in[1];   // [3D,D]
  const float* bqkv = (const float*)d_in[2];   // [3D]
  const float* Wgate = (const float*)d_in[3];  // [D,D]
  const float* bgate = (const float*)d_in[4];  // [D]
  float* out = (float*)d_out;

  char* ws = (char*)d_ws;
  unsigned short* xb = (unsigned short*)ws;                        // 32 MB bf16 x
  unsigned short* wb = (unsigned short*)(ws + (size_t)33554432);   // 8 MB  bf16 permuted W
  unsigned short* Qd = (unsigned short*)(ws + (size_t)41943040);   // 32 MB
  unsigned short* KVd = (unsigned short*)(ws + (size_t)75497472);  // 32 MB
  unsigned short* Gd = (unsigned short*)(ws + (size_t)109051904);  // 32 MB
  float* part = (float*)(ws + (size_t)142606336);                  // 2 MB

  k_convert<<<2048, 256, 0, stream>>>(x, xb, MM * KK / 4);
  k_convert_wperm<<<4096, 256, 0, stream>>>(Wqkv, Wgate, wb);

  k_gemm3<<<1024, 512, 0, stream>>>(xb, wb, Qd, KVd, Gd, bqkv, bgate);

  k_pass1<<<BB * NCH, 256, 0, stream>>>(KVd, part);
  k_pass3<<<BB * NCH, 256, 0, stream>>>(Qd, KVd, Gd, part, out);
}

// Round 5
// 319.880 us; speedup vs baseline: 1.0556x; 1.0556x over previous
//
#include <hip/hip_runtime.h>
#include <hip/hip_bf16.h>

// Problem constants (B=4, S=4096, D=1024)
#define BB 4
#define SS 4096
#define DD 1024
#define MM (BB * SS)   // 16384 rows
#define KK DD          // 1024  reduction dim
#define NN (4 * DD)    // 4096  cols (permuted): [q | kv-interleaved | gate]

typedef __attribute__((ext_vector_type(8))) short bf16x8;
typedef __attribute__((ext_vector_type(4))) float f32x4;

__device__ __forceinline__ unsigned short f2bf(float f) {
  unsigned u = __float_as_uint(f);
  u += 0x7FFF + ((u >> 16) & 1);   // RNE
  return (unsigned short)(u >> 16);
}
__device__ __forceinline__ float bf2f(unsigned short h) {
  return __uint_as_float(((unsigned)h) << 16);
}

// ---------------------------------------------------------------- prep: all f32->bf16 converts
// blocks [0,4096): permuted weight rows; blocks [4096,8192): x convert (4 float4/thread).
// Weight permutation (row n): [0,1024)=q; [1024,3072)=16-col k/v interleave; [3072,4096)=gate.
__global__ __launch_bounds__(256) void k_prep(const float* __restrict__ x,
                                              const float* __restrict__ Wqkv,
                                              const float* __restrict__ Wgate,
                                              unsigned short* __restrict__ xb,
                                              unsigned short* __restrict__ wb) {
  int blk = blockIdx.x;
  if (blk < 4096) {
    int n = blk;
    const float* src;
    if (n < 1024) {
      src = Wqkv + (size_t)n * 1024;
    } else if (n < 3072) {
      int t = (n - 1024) >> 4;
      int d = ((t >> 1) << 4) + (n & 15);
      src = Wqkv + (size_t)(1024 + ((t & 1) << 10) + d) * 1024;
    } else {
      src = Wgate + (size_t)(n - 3072) * 1024;
    }
    unsigned short* o = wb + (size_t)n * 1024;
    int i = threadIdx.x * 4;
    float4 v = *(const float4*)(src + i);
    ushort4 u;
    u.x = f2bf(v.x); u.y = f2bf(v.y); u.z = f2bf(v.z); u.w = f2bf(v.w);
    *(ushort4*)(o + i) = u;
  } else {
    int i0 = (blk - 4096) * 1024 + threadIdx.x;
#pragma unroll
    for (int it = 0; it < 4; ++it) {
      int i = i0 + it * 256;
      float4 v = reinterpret_cast<const float4*>(x)[i];
      ushort4 u;
      u.x = f2bf(v.x); u.y = f2bf(v.y); u.z = f2bf(v.z); u.w = f2bf(v.w);
      reinterpret_cast<ushort4*>(xb)[i] = u;
    }
  }
}

// ---------------------------------------------------------------- 256x256 8-phase GEMM
// BM=BN=256, BK=64, 8 waves (2Mx4N), per-wave 128x64 out (8x4 frags). LDS 128KiB.
// T2 swizzle (FIXED): byte ^= ((row&7)<<4) within each 16KB half-tile region
// (full 3-bit slot spread -> 8 lanes/slot = ds_read_b128 minimum).
// Applied as: linear global_load_lds dest + inverse-swizzled global source + swizzled ds_read.
// 8 phases / 2 K-tiles; counted vmcnt(4) at ph4/ph8 only. Fused: bias, k*v, sigmoid,
// and per-32-row chunk partial sums of kv (pass1) in the epilogue.
#define VMW4() asm volatile("s_waitcnt vmcnt(4)" ::: "memory")
#define VMW0() asm volatile("s_waitcnt vmcnt(0)" ::: "memory")

__global__ __launch_bounds__(512, 2) void k_gemm3(const unsigned short* __restrict__ A,
                                                  const unsigned short* __restrict__ W,
                                                  unsigned short* __restrict__ Qd,
                                                  unsigned short* __restrict__ KVd,
                                                  unsigned short* __restrict__ Gd,
                                                  float* __restrict__ part,
                                                  const float* __restrict__ bqkv,
                                                  const float* __restrict__ bgate) {
  __shared__ unsigned short sm[65536];  // 128 KiB

  int bid0 = blockIdx.x;
  int bid = (bid0 & 7) * 128 + (bid0 >> 3);   // XCD swizzle (nwg=1024 %8==0 -> bijective)
  int tn = bid & 15, tm = bid >> 4;
  int m0 = tm * 256, n0 = tn * 256;

  int tid = threadIdx.x, wave = tid >> 6, lane = tid & 63;
  int wm = wave >> 2, wn = wave & 3;
  int r = lane & 15, g = lane >> 4;

  // ---- staging source (per-lane, inverse-swizzled).
  // Within-16KB-region byte pos L = c*8192 + tid*16; row(L)&7 = (tid>>3)&7.
  // swz(L) = L ^ (((L>>7)&7)<<4)  [involution, disjoint bits]
  int pt = tid * 16;
  int psw = pt ^ (((pt >> 7) & 7) << 4);
  int srow = psw >> 7;          // 0..63 (c round adds 64 rows)
  int scol = (psw & 127) >> 1;  // ushort col within 64-col K-slice
  const unsigned short* Ag = A + (size_t)(m0 + srow) * KK + scol;
  const unsigned short* Wg = W + (size_t)(n0 + srow) * KK + scol;

  // Stage one half-tile (128 rows x 64 cols = 16KB) = 2 x global_load_lds_dwordx4/thread.
#define STG_A(kt, h, d) do {                                                              \
    __builtin_amdgcn_global_load_lds(                                                     \
        (const __attribute__((address_space(1))) void*)(Ag + (size_t)(h)*131072 + (kt)*64), \
        (__attribute__((address_space(3))) void*)&sm[(d)*16384 + (h)*8192 + wave*512], 16, 0, 0); \
    __builtin_amdgcn_global_load_lds(                                                     \
        (const __attribute__((address_space(1))) void*)(Ag + (size_t)(h)*131072 + 65536 + (kt)*64), \
        (__attribute__((address_space(3))) void*)&sm[(d)*16384 + (h)*8192 + 4096 + wave*512], 16, 0, 0); \
  } while (0)
#define STG_B(kt, h, d) do {                                                              \
    __builtin_amdgcn_global_load_lds(                                                     \
        (const __attribute__((address_space(1))) void*)(Wg + (size_t)(h)*131072 + (kt)*64), \
        (__attribute__((address_space(3))) void*)&sm[32768 + (d)*16384 + (h)*8192 + wave*512], 16, 0, 0); \
    __builtin_amdgcn_global_load_lds(                                                     \
        (const __attribute__((address_space(1))) void*)(Wg + (size_t)(h)*131072 + 65536 + (kt)*64), \
        (__attribute__((address_space(3))) void*)&sm[32768 + (d)*16384 + (h)*8192 + 4096 + wave*512], 16, 0, 0); \
  } while (0)

  // ---- ds_read (swizzled): ushort addr = region + m*1024 + r*64 + ((ks*32 + g*8) ^ sx)
  int sx = (r & 7) << 3;
  int aX0 = (r * 64 + g * 8) ^ sx;
  int aX1 = (r * 64 + 32 + g * 8) ^ sx;
  int aReg = wm * 8192;                                       // + d*16384 + m*1024
  int bReg = 32768 + (wn >> 1) * 8192 + (wn & 1) * 4096;      // + d*16384 + n*1024

#define LDSA(d, m, ks) (*reinterpret_cast<const bf16x8*>(&sm[aReg + (d)*16384 + (m)*1024 + ((ks) ? aX1 : aX0)]))
#define LDSB(d, n, ks) (*reinterpret_cast<const bf16x8*>(&sm[bReg + (d)*16384 + (n)*1024 + ((ks) ? aX1 : aX0)]))

  f32x4 acc[8][4] = {};
  bf16x8 a[4][2], Bn[4][2];

#define RD_A(d, mb) do { _Pragma("unroll") for (int mi = 0; mi < 4; ++mi) {               \
    _Pragma("unroll") for (int ks = 0; ks < 2; ++ks) { a[mi][ks] = LDSA(d, (mb)+mi, ks); } } } while (0)
#define RD_B(d, nb) do { _Pragma("unroll") for (int ni = 0; ni < 2; ++ni) {               \
    _Pragma("unroll") for (int ks = 0; ks < 2; ++ks) { Bn[(nb)+ni][ks] = LDSB(d, (nb)+ni, ks); } } } while (0)

#define BARW() do { __builtin_amdgcn_s_barrier();                                         \
    asm volatile("s_waitcnt lgkmcnt(0)" ::: "memory");                                    \
    __builtin_amdgcn_sched_barrier(0); } while (0)
#define ENDB() __builtin_amdgcn_s_barrier()

#define MFMA16(mb, nb) do {                                                               \
    __builtin_amdgcn_s_setprio(1);                                                        \
    _Pragma("unroll") for (int mi = 0; mi < 4; ++mi) {                                    \
      _Pragma("unroll") for (int ni = 0; ni < 2; ++ni) {                                  \
        _Pragma("unroll") for (int ks = 0; ks < 2; ++ks) {                                \
          acc[(mb)+mi][(nb)+ni] = __builtin_amdgcn_mfma_f32_16x16x32_bf16(                \
              a[mi][ks], Bn[(nb)+ni][ks], acc[(mb)+mi][(nb)+ni], 0, 0, 0);                \
        } } }                                                                             \
    __builtin_amdgcn_s_setprio(0); } while (0)

  // ---- prologue: T0 (dbuf0, all 4 half-tiles) + B-T1 (dbuf1)
  STG_A(0, 0, 0); STG_A(0, 1, 0);
  STG_B(0, 0, 0); STG_B(0, 1, 0);
  STG_B(1, 0, 1); STG_B(1, 1, 1);
  VMW4();
  __builtin_amdgcn_s_barrier();

  // ---- main loop: 7 iters x 2 K-tiles (T0..T13); peeled final (T14,T15)
  for (int i = 0; i < 7; ++i) {
    int tb = 2 * i + 1, tc = 2 * i + 2, td = 2 * i + 3;
    RD_A(0, 0); RD_B(0, 0); STG_A(tb, 0, 1);
    BARW(); MFMA16(0, 0); ENDB();
    RD_B(0, 2); STG_A(tb, 1, 1);
    BARW(); MFMA16(0, 2); ENDB();
    RD_A(0, 4); STG_B(tc, 0, 0);
    BARW(); MFMA16(4, 0); ENDB();
    STG_B(tc, 1, 0);
    BARW(); MFMA16(4, 2); VMW4(); ENDB();
    RD_A(1, 0); RD_B(1, 0); STG_A(tc, 0, 0);
    BARW(); MFMA16(0, 0); ENDB();
    RD_B(1, 2); STG_A(tc, 1, 0);
    BARW(); MFMA16(0, 2); ENDB();
    RD_A(1, 4); STG_B(td, 0, 1);
    BARW(); MFMA16(4, 0); ENDB();
    STG_B(td, 1, 1);
    BARW(); MFMA16(4, 2); VMW4(); ENDB();
  }
  RD_A(0, 0); RD_B(0, 0); STG_A(15, 0, 1);
  BARW(); MFMA16(0, 0); ENDB();
  RD_B(0, 2); STG_A(15, 1, 1);
  BARW(); MFMA16(0, 2); ENDB();
  RD_A(0, 4);
  BARW(); MFMA16(4, 0); ENDB();
  BARW(); MFMA16(4, 2); VMW0(); ENDB();
  RD_A(1, 0); RD_B(1, 0);
  BARW(); MFMA16(0, 0); ENDB();
  RD_B(1, 2);
  BARW(); MFMA16(0, 2); ENDB();
  RD_A(1, 4);
  BARW(); MFMA16(4, 0); ENDB();
  BARW(); MFMA16(4, 2);

  // ---- epilogue (C/D layout col=lane&15, row=(lane>>4)*4+q)
  int growb = m0 + wm * 128 + g * 4;
  if (tn < 4) {
#pragma unroll
    for (int n = 0; n < 4; ++n) {
      int col = n0 + wn * 64 + n * 16 + r;
      float bias = bqkv[col];
#pragma unroll
      for (int m = 0; m < 8; ++m)
#pragma unroll
        for (int q = 0; q < 4; ++q)
          Qd[(size_t)(growb + m * 16 + q) * DD + col] = f2bf(acc[m][n][q] + bias);
    }
  } else if (tn < 12) {
    // kv region + fused pass1 chunk partials (chunks of 32 rows)
    int dbase = ((n0 - 1024) >> 1) + (wn * 32);
#pragma unroll
    for (int np = 0; np < 2; ++np) {
      int d = dbase + np * 16 + r;
      float bk = bqkv[1024 + d], bv = bqkv[2048 + d];
      float pairsum = 0.f;
#pragma unroll
      for (int m = 0; m < 8; ++m) {
        float ps = 0.f;
#pragma unroll
        for (int q = 0; q < 4; ++q) {
          float kvv = (acc[m][2 * np][q] + bk) * (acc[m][2 * np + 1][q] + bv);
          KVd[(size_t)(growb + m * 16 + q) * DD + d] = f2bf(kvv);
          ps += kvv;
        }
        ps += __shfl_xor(ps, 16, 64);   // reduce across g groups
        ps += __shfl_xor(ps, 32, 64);
        if ((m & 1) == 0) {
          pairsum = ps;
        } else {
          pairsum += ps;
          if (lane < 16) {  // g==0 lanes write the chunk partial
            int cg = tm * 8 + wm * 4 + (m >> 1);  // global chunk id = row/32
            part[(size_t)cg * DD + d] = pairsum;
          }
        }
      }
    }
  } else {
    int cb0 = n0 - 3072;
#pragma unroll
    for (int n = 0; n < 4; ++n) {
      int c = cb0 + wn * 64 + n * 16 + r;
      float bias = bgate[c];
#pragma unroll
      for (int m = 0; m < 8; ++m)
#pragma unroll
        for (int q = 0; q < 4; ++q) {
          float gv = acc[m][n][q] + bias;
          Gd[(size_t)(growb + m * 16 + q) * DD + c] = f2bf(1.f / (1.f + __expf(-gv)));
        }
    }
  }
#undef STG_A
#undef STG_B
#undef LDSA
#undef LDSB
#undef RD_A
#undef RD_B
#undef BARW
#undef ENDB
#undef MFMA16
}

// ---------------------------------------------------------------- final pass
#define NCH 128
#define CSZ (SS / NCH)  // 32

// on-the-fly exclusive chunk prefix (part L2-resident) + local cumsum
// + out = q * kv_state * g (g pre-sigmoided)
__global__ __launch_bounds__(256) void k_pass3(const unsigned short* __restrict__ Q,
                                               const unsigned short* __restrict__ KV,
                                               const unsigned short* __restrict__ G,
                                               const float* __restrict__ part,
                                               float* __restrict__ out) {
  int b = blockIdx.x >> 7;
  int c = blockIdx.x & (NCH - 1);
  int d = threadIdx.x * 4;
  float4 a = {0.f, 0.f, 0.f, 0.f};
  const float* pb = &part[(size_t)b * NCH * DD + d];
  for (int cc = 0; cc < c; ++cc) {
    float4 p = *(const float4*)(pb + (size_t)cc * DD);
    a.x += p.x; a.y += p.y; a.z += p.z; a.w += p.w;
  }
  for (int s = c * CSZ; s < (c + 1) * CSZ; ++s) {
    size_t rowb = (size_t)(b * SS + s) * DD;
    ushort4 q4 = *(const ushort4*)&Q[rowb + d];
    ushort4 kv4 = *(const ushort4*)&KV[rowb + d];
    ushort4 g4 = *(const ushort4*)&G[rowb + d];
    a.x += bf2f(kv4.x); a.y += bf2f(kv4.y); a.z += bf2f(kv4.z); a.w += bf2f(kv4.w);
    float4 o;
    o.x = bf2f(q4.x) * a.x * bf2f(g4.x);
    o.y = bf2f(q4.y) * a.y * bf2f(g4.y);
    o.z = bf2f(q4.z) * a.z * bf2f(g4.z);
    o.w = bf2f(q4.w) * a.w * bf2f(g4.w);
    *(float4*)&out[rowb + d] = o;
  }
}

// ---------------------------------------------------------------- launch
extern "C" void kernel_launch(void* const* d_in, const int* in_sizes, int n_in,
                              void* d_out, int out_size, void* d_ws, size_t ws_size,
                              hipStream_t stream) {
  const float* x = (const float*)d_in[0];      // [B,S,D]
  const float* Wqkv = (const float*)d_in[1];   // [3D,D]
  const float* bqkv = (const float*)d_in[2];   // [3D]
  const float* Wgate = (const float*)d_in[3];  // [D,D]
  const float* bgate = (const float*)d_in[4];  // [D]
  float* out = (float*)d_out;

  char* ws = (char*)d_ws;
  unsigned short* xb = (unsigned short*)ws;                        // 32 MB bf16 x
  unsigned short* wb = (unsigned short*)(ws + (size_t)33554432);   // 8 MB  bf16 permuted W
  unsigned short* Qd = (unsigned short*)(ws + (size_t)41943040);   // 32 MB
  unsigned short* KVd = (unsigned short*)(ws + (size_t)75497472);  // 32 MB
  unsigned short* Gd = (unsigned short*)(ws + (size_t)109051904);  // 32 MB
  float* part = (float*)(ws + (size_t)142606336);                  // 2 MB [512 chunks][1024]

  k_prep<<<8192, 256, 0, stream>>>(x, Wqkv, Wgate, xb, wb);
  k_gemm3<<<1024, 512, 0, stream>>>(xb, wb, Qd, KVd, Gd, part, bqkv, bgate);
  k_pass3<<<BB * NCH, 256, 0, stream>>>(Qd, KVd, Gd, part, out);
}